// Round 2
// baseline (848.304 us; speedup 1.0000x reference)
//
#include <hip/hip_runtime.h>
#include <hip/hip_bf16.h>
#include <stdint.h>
#include <math.h>

#define T_TOK 8192
#define HID   2048
#define NH    16
#define NKV   8
#define HD    128
#define LSEQ  1024
#define BATCH 8
#define QKV_N 4096
#define KDIM  2048
#define SCALE 0.08838834764831845f   // 1/sqrt(128)

typedef __hip_bfloat16 bf16;
typedef __bf16 bf16x8 __attribute__((ext_vector_type(8)));
typedef float  f32x4  __attribute__((ext_vector_type(4)));

typedef const void __attribute__((address_space(1)))* gas_ptr;
typedef void       __attribute__((address_space(3)))* las_ptr;

__device__ __forceinline__ float b2f(bf16 x) { return __bfloat162float(x); }
__device__ __forceinline__ bf16  f2b(float x) { return __float2bfloat16(x); }
__device__ __forceinline__ unsigned short f2u(float x) {
    union { bf16 b; unsigned short u; } c; c.b = __float2bfloat16(x); return c.u;
}

__device__ __forceinline__ bf16x8 ld16(const bf16* p) {
    union { uint4 u; bf16x8 v; } c;
    c.u = *reinterpret_cast<const uint4*>(p);
    return c.v;
}

// async 16B/lane global->LDS. lds must be wave-uniform base; HW adds lane*16.
__device__ __forceinline__ void cp16(void* lds, const void* g) {
    __builtin_amdgcn_global_load_lds((gas_ptr)g, (las_ptr)lds, 16, 0, 0);
}

// ---------------- fp32 -> bf16 convert (grid-stride, vectorized) -------------
__global__ __launch_bounds__(256) void k_f2b(const float* __restrict__ in,
                                             bf16* __restrict__ out, int n) {
    int i = blockIdx.x * blockDim.x + threadIdx.x;
    int stride = gridDim.x * blockDim.x;
    const float4* in4 = (const float4*)in;
    ushort4* out4 = (ushort4*)out;
    int n4 = n >> 2;
    for (int j = i; j < n4; j += stride) {
        float4 v = in4[j];
        ushort4 o;
        o.x = f2u(v.x); o.y = f2u(v.y); o.z = f2u(v.z); o.w = f2u(v.w);
        out4[j] = o;
    }
}

// ---------------- modality map ----------------------------------------------
__global__ __launch_bounds__(256) void k_mod(const int* __restrict__ und,
                                             const int* __restrict__ gen,
                                             int* __restrict__ mod, int n) {
    int i = blockIdx.x * blockDim.x + threadIdx.x;
    if (i < n) { mod[und[i]] = 0; mod[gen[i]] = 1; }
}

// ---------------- routed GEMM (m97 structure), both modalities in one grid ---
// C[idx[row]][col] = sum_k A[idx[row]][k] * Bw[col][k]  (+ bias, EPI==0)
// EPI 0: qkv -> bf16 out (row stride QKV_N), bias by col range
// EPI 1: out-proj -> f32 out (row stride HID), no bias
template<int EPI>
__global__ __launch_bounds__(256)
void k_gemm(const bf16* __restrict__ A,
            const bf16* __restrict__ Bw_u, const bf16* __restrict__ Bw_g,
            const int* __restrict__ und, const int* __restrict__ gen,
            const float* __restrict__ bq_u, const float* __restrict__ bk_u,
            const float* __restrict__ bv_u,
            const float* __restrict__ bq_g, const float* __restrict__ bk_g,
            const float* __restrict__ bv_g,
            bf16* __restrict__ outB, float* __restrict__ outF, int ntilesN) {
    __shared__ bf16 sA[128][32];
    __shared__ bf16 sB[128][32];

    int modg = blockIdx.y;
    const bf16* Bw = modg ? Bw_g : Bw_u;
    const int* idx = modg ? gen : und;
    const float* bq = modg ? bq_g : bq_u;
    const float* bk = modg ? bk_g : bk_u;
    const float* bv = modg ? bv_g : bv_u;

    int tile = blockIdx.x;
    int tn = tile % ntilesN, tm = tile / ntilesN;
    int tid = threadIdx.x;
    int w = tid >> 6, lane = tid & 63;
    int l16 = lane & 15, l4 = lane >> 4;
    int wrow = w >> 1, wcol = w & 1;

    // staging source pointers (per-lane); LDS layout is exactly linear c*16B
    const bf16* pA[2]; const bf16* pB[2];
    uint32_t ldsOff[2];
#pragma unroll
    for (int it = 0; it < 2; ++it) {
        int c = it * 256 + w * 64 + lane;
        int row = c >> 2, kc = (c & 3) * 8;
        pA[it] = A + (size_t)idx[tm * 128 + row] * KDIM + kc;
        pB[it] = Bw + (size_t)(tn * 128 + row) * KDIM + kc;
        ldsOff[it] = (uint32_t)(it * 256 + w * 64) * 16;  // wave-uniform base
    }
    char* sAb = (char*)&sA[0][0];
    char* sBb = (char*)&sB[0][0];

    f32x4 zero = {0.f, 0.f, 0.f, 0.f};
    f32x4 acc[4][4];
#pragma unroll
    for (int m = 0; m < 4; ++m)
#pragma unroll
        for (int n = 0; n < 4; ++n) acc[m][n] = zero;

    for (int k0 = 0; k0 < KDIM; k0 += 32) {
        cp16(sAb + ldsOff[0], pA[0] + k0);
        cp16(sAb + ldsOff[1], pA[1] + k0);
        cp16(sBb + ldsOff[0], pB[0] + k0);
        cp16(sBb + ldsOff[1], pB[1] + k0);
        __syncthreads();   // drains vmcnt -> tiles resident
        bf16x8 af[4], bfr[4];
#pragma unroll
        for (int m = 0; m < 4; ++m) af[m] = ld16(&sA[wrow * 64 + m * 16 + l16][l4 * 8]);
#pragma unroll
        for (int n = 0; n < 4; ++n) bfr[n] = ld16(&sB[wcol * 64 + n * 16 + l16][l4 * 8]);
#pragma unroll
        for (int m = 0; m < 4; ++m)
#pragma unroll
            for (int n = 0; n < 4; ++n)
                acc[m][n] = __builtin_amdgcn_mfma_f32_16x16x32_bf16(af[m], bfr[n], acc[m][n], 0, 0, 0);
        __syncthreads();   // compute done before next overwrite
    }

    int rowbase = tm * 128 + wrow * 64;
    int colbase = tn * 128 + wcol * 64;
#pragma unroll
    for (int m = 0; m < 4; ++m) {
#pragma unroll
        for (int r = 0; r < 4; ++r) {
            int row = rowbase + m * 16 + l4 * 4 + r;
            int token = idx[row];
#pragma unroll
            for (int n = 0; n < 4; ++n) {
                int col = colbase + n * 16 + l16;
                float v = acc[m][n][r];
                if (EPI == 0) {
                    float bias = (col < 2048) ? bq[col]
                               : (col < 3072) ? bk[col - 2048] : bv[col - 3072];
                    outB[(size_t)token * QKV_N + col] = f2b(v + bias);
                } else {
                    outF[(size_t)token * HID + col] = v;
                }
            }
        }
    }
}

// ---------------- per-head RMSNorm + RoPE (Q,K only) -------------------------
__global__ __launch_bounds__(256)
void k_normrope(const bf16* __restrict__ qkv,
                const float* __restrict__ cosT, const float* __restrict__ sinT,
                const int* __restrict__ mod,
                const float* __restrict__ qn_u, const float* __restrict__ qn_g,
                const float* __restrict__ kn_u, const float* __restrict__ kn_g,
                bf16* __restrict__ Qo, bf16* __restrict__ Ko) {
    int t = blockIdx.x;
    int tid = threadIdx.x;
    int w = tid >> 6, lane = tid & 63;
    int m = mod[t];
    int b = t >> 10, pos = t & 1023;
    const bf16* row = qkv + (size_t)t * QKV_N;
    int d0 = 2 * lane, d1 = 2 * lane + 1;
    float c0 = cosT[(size_t)t * HD + d0], c1 = cosT[(size_t)t * HD + d1];
    float s0 = sinT[(size_t)t * HD + d0], s1 = sinT[(size_t)t * HD + d1];
    float sgn = (lane < 32) ? -1.f : 1.f;   // rot_half sign: d<64 -> -x[d+64]
    const float* qw = m ? qn_g : qn_u;
    const float* kw = m ? kn_g : kn_u;

    for (int u = w; u < 24; u += 4) {   // 0..15 q-heads, 16..23 k-heads
        float v0 = b2f(row[u * HD + d0]);
        float v1 = b2f(row[u * HD + d1]);
        float ss = v0 * v0 + v1 * v1;
#pragma unroll
        for (int msk = 1; msk < 64; msk <<= 1) ss += __shfl_xor(ss, msk);
        float rs = rsqrtf(ss * (1.0f / HD) + 1e-6f);
        const float* wsc = (u < 16) ? qw : kw;
        float n0 = v0 * rs * wsc[d0], n1 = v1 * rs * wsc[d1];
        float o0 = __shfl_xor(n0, 32), o1 = __shfl_xor(n1, 32);
        float r0 = n0 * c0 + sgn * o0 * s0;
        float r1 = n1 * c1 + sgn * o1 * s1;
        if (u < 16) {
            size_t o = ((size_t)(b * NH + u) * LSEQ + pos) * HD;
            Qo[o + d0] = f2b(r0); Qo[o + d1] = f2b(r1);
        } else {
            size_t o = ((size_t)(b * NKV + (u - 16)) * LSEQ + pos) * HD;
            Ko[o + d0] = f2b(r0); Ko[o + d1] = f2b(r1);
        }
    }
}

// ---------------- V transpose: qkv[t][3072+kv*128+d] -> Vt[b,kv][d][pos] -----
__global__ __launch_bounds__(256)
void k_vt(const bf16* __restrict__ qkv, bf16* __restrict__ Vt) {
    __shared__ bf16 lds[64][72];   // pad 64->72 (16B-aligned rows, no conflicts)
    int bk = blockIdx.x;           // b*8+kv
    int b = bk >> 3, kv = bk & 7;
    int pos0 = blockIdx.y * 64;
    int d0 = blockIdx.z * 64;
    int tid = threadIdx.x;

    // load 64(pos) x 64(d) tile, 16B per chunk
#pragma unroll
    for (int it = 0; it < 2; ++it) {
        int c = tid + it * 256;
        int row = c >> 3, col8 = (c & 7) * 8;
        const bf16* src = qkv + (size_t)(b * LSEQ + pos0 + row) * QKV_N
                        + 3072 + kv * HD + d0 + col8;
        *reinterpret_cast<uint4*>(&lds[row][col8]) = *reinterpret_cast<const uint4*>(src);
    }
    __syncthreads();

    // store transposed: row d, 8 consecutive pos per chunk
#pragma unroll
    for (int it = 0; it < 2; ++it) {
        int c = tid + it * 256;
        int drow = c & 63, pos8 = (c >> 6) * 8;
        union { unsigned short s[8]; uint4 u; } g;
#pragma unroll
        for (int j = 0; j < 8; ++j)
            g.s[j] = *reinterpret_cast<const unsigned short*>(&lds[pos8 + j][drow]);
        bf16* dst = Vt + ((size_t)bk * HD + d0 + drow) * LSEQ + pos0 + pos8;
        *reinterpret_cast<uint4*>(dst) = g.u;
    }
}

// ---------------- causal GQA flash attention ---------------------------------
// block = (b, h, 64 q rows); 4 independent waves x 16 q rows. K read from
// global (L2-resident); V read from pre-transposed Vt (vector fragments);
// P transposed via per-wave LDS.
__global__ __launch_bounds__(256)
void k_attn(const bf16* __restrict__ Q, const bf16* __restrict__ K,
            const bf16* __restrict__ Vt, bf16* __restrict__ O) {
    int bid = blockIdx.x;
    int qblk = bid & 15;
    int h = (bid >> 4) & 15;
    int b = bid >> 8;
    int tid = threadIdx.x;
    int w = tid >> 6, lane = tid & 63;
    int l16 = lane & 15, l4 = lane >> 4;
    int q0 = qblk * 64 + w * 16;

    const bf16* qb = Q + ((size_t)(b * NH + h) * LSEQ + q0) * HD;
    int kv = h >> 1;
    const bf16* kb = K + (size_t)(b * NKV + kv) * LSEQ * HD;
    const bf16* vtb = Vt + (size_t)(b * NKV + kv) * HD * LSEQ;

    bf16x8 qf[4];
#pragma unroll
    for (int c = 0; c < 4; ++c) qf[c] = ld16(qb + l16 * HD + c * 32 + l4 * 8);

    f32x4 zero = {0.f, 0.f, 0.f, 0.f};
    f32x4 oacc[8];
#pragma unroll
    for (int d = 0; d < 8; ++d) oacc[d] = zero;
    float mr[4] = {-INFINITY, -INFINITY, -INFINITY, -INFINITY};
    float lr[4] = {0.f, 0.f, 0.f, 0.f};

    __shared__ bf16 Pl[4][16][40];   // per-wave P tile, padded 32->40 (banks)

    int kend = q0 + 16;   // this wave needs keys < kend
    for (int kt = 0; kt < kend; kt += 32) {
        f32x4 s0 = zero, s1 = zero;
#pragma unroll
        for (int c = 0; c < 4; ++c) {
            bf16x8 k0f = ld16(kb + (size_t)(kt + l16) * HD + c * 32 + l4 * 8);
            bf16x8 k1f = ld16(kb + (size_t)(kt + 16 + l16) * HD + c * 32 + l4 * 8);
            s0 = __builtin_amdgcn_mfma_f32_16x16x32_bf16(qf[c], k0f, s0, 0, 0, 0);
            s1 = __builtin_amdgcn_mfma_f32_16x16x32_bf16(qf[c], k1f, s1, 0, 0, 0);
        }
        float p0v[4], p1v[4];
#pragma unroll
        for (int r = 0; r < 4; ++r) {
            int qrow = q0 + l4 * 4 + r;
            float sc0 = (kt + l16 <= qrow) ? s0[r] * SCALE : -1e30f;
            float sc1 = (kt + 16 + l16 <= qrow) ? s1[r] * SCALE : -1e30f;
            float rm = fmaxf(sc0, sc1);
#pragma unroll
            for (int msk = 1; msk < 16; msk <<= 1) rm = fmaxf(rm, __shfl_xor(rm, msk));
            float mn = fmaxf(mr[r], rm);
            float corr = __expf(mr[r] - mn);
            float p0 = __expf(sc0 - mn);
            float p1 = __expf(sc1 - mn);
            float rsum = p0 + p1;
#pragma unroll
            for (int msk = 1; msk < 16; msk <<= 1) rsum += __shfl_xor(rsum, msk);
            lr[r] = lr[r] * corr + rsum;
            mr[r] = mn;
#pragma unroll
            for (int d = 0; d < 8; ++d) oacc[d][r] = oacc[d][r] * corr;
            p0v[r] = p0; p1v[r] = p1;
        }
        // P transpose round-trip (per-wave private; compiler orders via lgkmcnt)
#pragma unroll
        for (int r = 0; r < 4; ++r) {
            Pl[w][l4 * 4 + r][l16] = f2b(p0v[r]);
            Pl[w][l4 * 4 + r][16 + l16] = f2b(p1v[r]);
        }
        bf16x8 pf = ld16(&Pl[w][l16][l4 * 8]);
#pragma unroll
        for (int dt = 0; dt < 8; ++dt) {
            bf16x8 vfr = ld16(vtb + (size_t)(dt * 16 + l16) * LSEQ + kt + l4 * 8);
            oacc[dt] = __builtin_amdgcn_mfma_f32_16x16x32_bf16(pf, vfr, oacc[dt], 0, 0, 0);
        }
    }
#pragma unroll
    for (int r = 0; r < 4; ++r) lr[r] = 1.0f / lr[r];
    int trow = b * LSEQ + q0;
#pragma unroll
    for (int dt = 0; dt < 8; ++dt)
#pragma unroll
        for (int r = 0; r < 4; ++r) {
            int t = trow + l4 * 4 + r;
            O[(size_t)t * HID + h * HD + dt * 16 + l16] = f2b(oacc[dt][r] * lr[r]);
        }
}

// ---------------- launch -----------------------------------------------------
extern "C" void kernel_launch(void* const* d_in, const int* in_sizes, int n_in,
                              void* d_out, int out_size, void* d_ws, size_t ws_size,
                              hipStream_t stream) {
    const float* x    = (const float*)d_in[0];
    const float* cosT = (const float*)d_in[1];
    const float* sinT = (const float*)d_in[2];
    // d_in[3] attention_mask: pure causal, reimplemented in-kernel
    const int* und = (const int*)d_in[4];
    const int* gen = (const int*)d_in[5];
    const float* Wq_u = (const float*)d_in[6];
    const float* bq_u = (const float*)d_in[7];
    const float* Wk_u = (const float*)d_in[8];
    const float* bk_u = (const float*)d_in[9];
    const float* Wv_u = (const float*)d_in[10];
    const float* bv_u = (const float*)d_in[11];
    const float* Wo_u = (const float*)d_in[12];
    const float* Wq_g = (const float*)d_in[13];
    const float* bq_g = (const float*)d_in[14];
    const float* Wk_g = (const float*)d_in[15];
    const float* bk_g = (const float*)d_in[16];
    const float* Wv_g = (const float*)d_in[17];
    const float* bv_g = (const float*)d_in[18];
    const float* Wo_g = (const float*)d_in[19];
    const float* qn_u = (const float*)d_in[20];
    const float* kn_u = (const float*)d_in[21];
    const float* qn_g = (const float*)d_in[22];
    const float* kn_g = (const float*)d_in[23];
    float* out = (float*)d_out;

    char* ws = (char*)d_ws;
    size_t off = 0;
    auto alloc = [&](size_t bytes) -> void* {
        void* p = ws + off;
        off += (bytes + 255) & ~(size_t)255;
        return p;
    };
    bf16* xb      = (bf16*)alloc((size_t)T_TOK * HID * 2);
    bf16* Wqkv_u  = (bf16*)alloc((size_t)QKV_N * KDIM * 2);
    bf16* Wqkv_g  = (bf16*)alloc((size_t)QKV_N * KDIM * 2);
    bf16* Wob_u   = (bf16*)alloc((size_t)HID * HID * 2);
    bf16* Wob_g   = (bf16*)alloc((size_t)HID * HID * 2);
    int*  mod     = (int*)alloc((size_t)T_TOK * 4);
    bf16* qkv     = (bf16*)alloc((size_t)T_TOK * QKV_N * 2);
    bf16* Qa      = (bf16*)alloc((size_t)BATCH * NH  * LSEQ * HD * 2);
    bf16* Ka      = (bf16*)alloc((size_t)BATCH * NKV * LSEQ * HD * 2);
    bf16* Vt      = (bf16*)alloc((size_t)BATCH * NKV * HD * LSEQ * 2);
    bf16* Ob      = (bf16*)alloc((size_t)T_TOK * HID * 2);
    (void)ws_size; (void)in_sizes; (void)n_in; (void)out_size;

    // converts
    k_f2b<<<1024, 256, 0, stream>>>(x, xb, T_TOK * HID);
    k_f2b<<<1024, 256, 0, stream>>>(Wq_u, Wqkv_u,               2048 * 2048);
    k_f2b<<<1024, 256, 0, stream>>>(Wk_u, Wqkv_u + 2048 * 2048, 1024 * 2048);
    k_f2b<<<1024, 256, 0, stream>>>(Wv_u, Wqkv_u + 3072 * 2048, 1024 * 2048);
    k_f2b<<<1024, 256, 0, stream>>>(Wq_g, Wqkv_g,               2048 * 2048);
    k_f2b<<<1024, 256, 0, stream>>>(Wk_g, Wqkv_g + 2048 * 2048, 1024 * 2048);
    k_f2b<<<1024, 256, 0, stream>>>(Wv_g, Wqkv_g + 3072 * 2048, 1024 * 2048);
    k_f2b<<<1024, 256, 0, stream>>>(Wo_u, Wob_u, 2048 * 2048);
    k_f2b<<<1024, 256, 0, stream>>>(Wo_g, Wob_g, 2048 * 2048);
    k_mod<<<16, 256, 0, stream>>>(und, gen, mod, T_TOK / 2);

    // routed QKV projections (M=4096, N=4096, K=2048; both modalities)
    k_gemm<0><<<dim3(32 * 32, 2), 256, 0, stream>>>(
        xb, Wqkv_u, Wqkv_g, und, gen, bq_u, bk_u, bv_u, bq_g, bk_g, bv_g,
        qkv, nullptr, 32);

    // RMS + RoPE (Q,K) and V transpose
    k_normrope<<<T_TOK, 256, 0, stream>>>(qkv, cosT, sinT, mod,
                                          qn_u, qn_g, kn_u, kn_g, Qa, Ka);
    k_vt<<<dim3(BATCH * NKV, LSEQ / 64, HD / 64), 256, 0, stream>>>(qkv, Vt);

    // causal GQA attention
    k_attn<<<BATCH * NH * (LSEQ / 64), 256, 0, stream>>>(Qa, Ka, Vt, Ob);

    // routed output projections (M=4096, N=2048, K=2048; both modalities)
    k_gemm<1><<<dim3(32 * 16, 2), 256, 0, stream>>>(
        Ob, Wob_u, Wob_g, und, gen, nullptr, nullptr, nullptr,
        nullptr, nullptr, nullptr, nullptr, out, 16);
}

// Round 3
// 546.575 us; speedup vs baseline: 1.5520x; 1.5520x over previous
//
#include <hip/hip_runtime.h>
#include <hip/hip_bf16.h>
#include <stdint.h>
#include <math.h>

#define T_TOK 8192
#define HID   2048
#define NH    16
#define NKV   8
#define HD    128
#define LSEQ  1024
#define BATCH 8
#define QKV_N 4096
#define KDIM  2048
#define SCALE 0.08838834764831845f   // 1/sqrt(128)

typedef __hip_bfloat16 bf16;
typedef __bf16 bf16x8 __attribute__((ext_vector_type(8)));
typedef float  f32x4  __attribute__((ext_vector_type(4)));

typedef const void __attribute__((address_space(1)))* gas_ptr;
typedef void       __attribute__((address_space(3)))* las_ptr;

__device__ __forceinline__ float b2f(bf16 x) { return __bfloat162float(x); }
__device__ __forceinline__ bf16  f2b(float x) { return __float2bfloat16(x); }
__device__ __forceinline__ unsigned short f2u(float x) {
    union { bf16 b; unsigned short u; } c; c.b = __float2bfloat16(x); return c.u;
}

__device__ __forceinline__ bf16x8 ld16(const bf16* p) {
    union { uint4 u; bf16x8 v; } c;
    c.u = *reinterpret_cast<const uint4*>(p);
    return c.v;
}

// async 16B/lane global->LDS. lds must be wave-uniform base; HW adds lane*16.
__device__ __forceinline__ void cp16(void* lds, const void* g) {
    __builtin_amdgcn_global_load_lds((gas_ptr)g, (las_ptr)lds, 16, 0, 0);
}

// ---------------- fp32 -> bf16 convert (grid-stride, vectorized) -------------
__global__ __launch_bounds__(256) void k_f2b(const float* __restrict__ in,
                                             bf16* __restrict__ out, int n) {
    int i = blockIdx.x * blockDim.x + threadIdx.x;
    int stride = gridDim.x * blockDim.x;
    const float4* in4 = (const float4*)in;
    ushort4* out4 = (ushort4*)out;
    int n4 = n >> 2;
    for (int j = i; j < n4; j += stride) {
        float4 v = in4[j];
        ushort4 o;
        o.x = f2u(v.x); o.y = f2u(v.y); o.z = f2u(v.z); o.w = f2u(v.w);
        out4[j] = o;
    }
}

// ---------------- modality map ----------------------------------------------
__global__ __launch_bounds__(256) void k_mod(const int* __restrict__ und,
                                             const int* __restrict__ gen,
                                             int* __restrict__ mod, int n) {
    int i = blockIdx.x * blockDim.x + threadIdx.x;
    if (i < n) { mod[und[i]] = 0; mod[gen[i]] = 1; }
}

// ---------------- routed GEMM (m97 structure), both modalities in one grid ---
template<int EPI>
__global__ __launch_bounds__(256)
void k_gemm(const bf16* __restrict__ A,
            const bf16* __restrict__ Bw_u, const bf16* __restrict__ Bw_g,
            const int* __restrict__ und, const int* __restrict__ gen,
            const float* __restrict__ bq_u, const float* __restrict__ bk_u,
            const float* __restrict__ bv_u,
            const float* __restrict__ bq_g, const float* __restrict__ bk_g,
            const float* __restrict__ bv_g,
            bf16* __restrict__ outB, float* __restrict__ outF, int ntilesN) {
    __shared__ bf16 sA[128][32];
    __shared__ bf16 sB[128][32];

    int modg = blockIdx.y;
    const bf16* Bw = modg ? Bw_g : Bw_u;
    const int* idx = modg ? gen : und;
    const float* bq = modg ? bq_g : bq_u;
    const float* bk = modg ? bk_g : bk_u;
    const float* bv = modg ? bv_g : bv_u;

    int tile = blockIdx.x;
    int tn = tile % ntilesN, tm = tile / ntilesN;
    int tid = threadIdx.x;
    int w = tid >> 6, lane = tid & 63;
    int l16 = lane & 15, l4 = lane >> 4;
    int wrow = w >> 1, wcol = w & 1;

    const bf16* pA[2]; const bf16* pB[2];
    uint32_t ldsOff[2];
#pragma unroll
    for (int it = 0; it < 2; ++it) {
        int c = it * 256 + w * 64 + lane;
        int row = c >> 2, kc = (c & 3) * 8;
        pA[it] = A + (size_t)idx[tm * 128 + row] * KDIM + kc;
        pB[it] = Bw + (size_t)(tn * 128 + row) * KDIM + kc;
        ldsOff[it] = (uint32_t)(it * 256 + w * 64) * 16;
    }
    char* sAb = (char*)&sA[0][0];
    char* sBb = (char*)&sB[0][0];

    f32x4 zero = {0.f, 0.f, 0.f, 0.f};
    f32x4 acc[4][4];
#pragma unroll
    for (int m = 0; m < 4; ++m)
#pragma unroll
        for (int n = 0; n < 4; ++n) acc[m][n] = zero;

    for (int k0 = 0; k0 < KDIM; k0 += 32) {
        cp16(sAb + ldsOff[0], pA[0] + k0);
        cp16(sAb + ldsOff[1], pA[1] + k0);
        cp16(sBb + ldsOff[0], pB[0] + k0);
        cp16(sBb + ldsOff[1], pB[1] + k0);
        __syncthreads();
        bf16x8 af[4], bfr[4];
#pragma unroll
        for (int m = 0; m < 4; ++m) af[m] = ld16(&sA[wrow * 64 + m * 16 + l16][l4 * 8]);
#pragma unroll
        for (int n = 0; n < 4; ++n) bfr[n] = ld16(&sB[wcol * 64 + n * 16 + l16][l4 * 8]);
#pragma unroll
        for (int m = 0; m < 4; ++m)
#pragma unroll
            for (int n = 0; n < 4; ++n)
                acc[m][n] = __builtin_amdgcn_mfma_f32_16x16x32_bf16(af[m], bfr[n], acc[m][n], 0, 0, 0);
        __syncthreads();
    }

    int rowbase = tm * 128 + wrow * 64;
    int colbase = tn * 128 + wcol * 64;
#pragma unroll
    for (int m = 0; m < 4; ++m) {
#pragma unroll
        for (int r = 0; r < 4; ++r) {
            int row = rowbase + m * 16 + l4 * 4 + r;
            int token = idx[row];
#pragma unroll
            for (int n = 0; n < 4; ++n) {
                int col = colbase + n * 16 + l16;
                float v = acc[m][n][r];
                if (EPI == 0) {
                    float bias = (col < 2048) ? bq[col]
                               : (col < 3072) ? bk[col - 2048] : bv[col - 3072];
                    outB[(size_t)token * QKV_N + col] = f2b(v + bias);
                } else {
                    outF[(size_t)token * HID + col] = v;
                }
            }
        }
    }
}

// ---------------- per-head RMSNorm + RoPE (Q,K only) -------------------------
__global__ __launch_bounds__(256)
void k_normrope(const bf16* __restrict__ qkv,
                const float* __restrict__ cosT, const float* __restrict__ sinT,
                const int* __restrict__ mod,
                const float* __restrict__ qn_u, const float* __restrict__ qn_g,
                const float* __restrict__ kn_u, const float* __restrict__ kn_g,
                bf16* __restrict__ Qo, bf16* __restrict__ Ko) {
    int t = blockIdx.x;
    int tid = threadIdx.x;
    int w = tid >> 6, lane = tid & 63;
    int m = mod[t];
    int b = t >> 10, pos = t & 1023;
    const bf16* row = qkv + (size_t)t * QKV_N;
    int d0 = 2 * lane, d1 = 2 * lane + 1;
    float c0 = cosT[(size_t)t * HD + d0], c1 = cosT[(size_t)t * HD + d1];
    float s0 = sinT[(size_t)t * HD + d0], s1 = sinT[(size_t)t * HD + d1];
    float sgn = (lane < 32) ? -1.f : 1.f;
    const float* qw = m ? qn_g : qn_u;
    const float* kw = m ? kn_g : kn_u;

    for (int u = w; u < 24; u += 4) {
        float v0 = b2f(row[u * HD + d0]);
        float v1 = b2f(row[u * HD + d1]);
        float ss = v0 * v0 + v1 * v1;
#pragma unroll
        for (int msk = 1; msk < 64; msk <<= 1) ss += __shfl_xor(ss, msk);
        float rs = rsqrtf(ss * (1.0f / HD) + 1e-6f);
        const float* wsc = (u < 16) ? qw : kw;
        float n0 = v0 * rs * wsc[d0], n1 = v1 * rs * wsc[d1];
        float o0 = __shfl_xor(n0, 32), o1 = __shfl_xor(n1, 32);
        float r0 = n0 * c0 + sgn * o0 * s0;
        float r1 = n1 * c1 + sgn * o1 * s1;
        if (u < 16) {
            size_t o = ((size_t)(b * NH + u) * LSEQ + pos) * HD;
            Qo[o + d0] = f2b(r0); Qo[o + d1] = f2b(r1);
        } else {
            size_t o = ((size_t)(b * NKV + (u - 16)) * LSEQ + pos) * HD;
            Ko[o + d0] = f2b(r0); Ko[o + d1] = f2b(r1);
        }
    }
}

// ---------------- V transpose: qkv[t][3072+kv*128+d] -> Vt[b,kv][d][pos] -----
__global__ __launch_bounds__(256)
void k_vt(const bf16* __restrict__ qkv, bf16* __restrict__ Vt) {
    __shared__ bf16 lds[64][72];
    int bk = blockIdx.x;
    int b = bk >> 3, kv = bk & 7;
    int pos0 = blockIdx.y * 64;
    int d0 = blockIdx.z * 64;
    int tid = threadIdx.x;

#pragma unroll
    for (int it = 0; it < 2; ++it) {
        int c = tid + it * 256;
        int row = c >> 3, col8 = (c & 7) * 8;
        const bf16* src = qkv + (size_t)(b * LSEQ + pos0 + row) * QKV_N
                        + 3072 + kv * HD + d0 + col8;
        *reinterpret_cast<uint4*>(&lds[row][col8]) = *reinterpret_cast<const uint4*>(src);
    }
    __syncthreads();

#pragma unroll
    for (int it = 0; it < 2; ++it) {
        int c = tid + it * 256;
        int drow = c & 63, pos8 = (c >> 6) * 8;
        union { unsigned short s[8]; uint4 u; } g;
#pragma unroll
        for (int j = 0; j < 8; ++j)
            g.s[j] = *reinterpret_cast<const unsigned short*>(&lds[pos8 + j][drow]);
        bf16* dst = Vt + ((size_t)bk * HD + d0 + drow) * LSEQ + pos0 + pos8;
        *reinterpret_cast<uint4*>(dst) = g.u;
    }
}

// ---------------- causal GQA flash attention (balanced, 32 q-rows/wave) ------
// Wave-task = 32 q-rows; wave j handles rowblks j and 31-j (equal 1056 keys).
// 64-key steps: 32 QK MFMA + softmax + 32 PV MFMA per step; K/V from global
// (L2-resident), P transposed via per-wave private LDS.
__global__ __launch_bounds__(256)
void k_attn(const bf16* __restrict__ Q, const bf16* __restrict__ K,
            const bf16* __restrict__ Vt, bf16* __restrict__ O) {
    int bid = blockIdx.x;
    int p = bid & 3;
    int h = (bid >> 2) & 15;
    int b = bid >> 6;
    int tid = threadIdx.x;
    int w = tid >> 6, lane = tid & 63;
    int l16 = lane & 15, l4 = lane >> 4;
    int j = p * 4 + w;

    const bf16* qhb = Q + (size_t)(b * NH + h) * LSEQ * HD;
    int kv = h >> 1;
    const bf16* kb = K + (size_t)(b * NKV + kv) * LSEQ * HD;
    const bf16* vtb = Vt + (size_t)(b * NKV + kv) * HD * LSEQ;

    __shared__ bf16 Pl[4][32][72];   // per-wave P tile (32 rows x 64 keys)

    f32x4 zero = {0.f, 0.f, 0.f, 0.f};

#pragma unroll 1
    for (int half = 0; half < 2; ++half) {
        int rowblk = half ? (31 - j) : j;
        int q0 = rowblk * 32;
        int kend = q0 + 32;

        bf16x8 qf[2][4];
#pragma unroll
        for (int rf = 0; rf < 2; ++rf)
#pragma unroll
            for (int c = 0; c < 4; ++c)
                qf[rf][c] = ld16(qhb + (size_t)(q0 + rf * 16 + l16) * HD + c * 32 + l4 * 8);

        f32x4 oacc[2][8];
#pragma unroll
        for (int rf = 0; rf < 2; ++rf)
#pragma unroll
            for (int d = 0; d < 8; ++d) oacc[rf][d] = zero;
        float mr[2][4], lr[2][4];
#pragma unroll
        for (int rf = 0; rf < 2; ++rf)
#pragma unroll
            for (int r = 0; r < 4; ++r) { mr[rf][r] = -INFINITY; lr[rf][r] = 0.f; }

        for (int kt = 0; kt < kend; kt += 64) {
            // ---- QK^T over 64 keys (masking handles tail overrun; kt+63<1024 always)
            f32x4 s[2][4];
#pragma unroll
            for (int rf = 0; rf < 2; ++rf)
#pragma unroll
                for (int kf = 0; kf < 4; ++kf) s[rf][kf] = zero;
#pragma unroll
            for (int c = 0; c < 4; ++c) {
                bf16x8 kf4[4];
#pragma unroll
                for (int kf = 0; kf < 4; ++kf)
                    kf4[kf] = ld16(kb + (size_t)(kt + kf * 16 + l16) * HD + c * 32 + l4 * 8);
#pragma unroll
                for (int rf = 0; rf < 2; ++rf)
#pragma unroll
                    for (int kf = 0; kf < 4; ++kf)
                        s[rf][kf] = __builtin_amdgcn_mfma_f32_16x16x32_bf16(qf[rf][c], kf4[kf], s[rf][kf], 0, 0, 0);
            }
            // ---- online softmax, write P to per-wave LDS
#pragma unroll
            for (int rf = 0; rf < 2; ++rf) {
#pragma unroll
                for (int r = 0; r < 4; ++r) {
                    int qrow = q0 + rf * 16 + l4 * 4 + r;
                    float sc[4];
                    float rm = -1e30f;
#pragma unroll
                    for (int kf = 0; kf < 4; ++kf) {
                        int key = kt + kf * 16 + l16;
                        sc[kf] = (key <= qrow) ? s[rf][kf][r] * SCALE : -1e30f;
                        rm = fmaxf(rm, sc[kf]);
                    }
#pragma unroll
                    for (int msk = 1; msk < 16; msk <<= 1) rm = fmaxf(rm, __shfl_xor(rm, msk));
                    float mn = fmaxf(mr[rf][r], rm);
                    float corr = __expf(mr[rf][r] - mn);
                    mr[rf][r] = mn;
                    float rsum = 0.f;
#pragma unroll
                    for (int kf = 0; kf < 4; ++kf) {
                        float pv = __expf(sc[kf] - mn);
                        rsum += pv;
                        Pl[w][rf * 16 + l4 * 4 + r][kf * 16 + l16] = f2b(pv);
                    }
#pragma unroll
                    for (int msk = 1; msk < 16; msk <<= 1) rsum += __shfl_xor(rsum, msk);
                    lr[rf][r] = lr[rf][r] * corr + rsum;
#pragma unroll
                    for (int d = 0; d < 8; ++d) oacc[rf][d][r] *= corr;
                }
            }
            // ---- PV: P (LDS) x V^T (global vector frags)
            bf16x8 pf[2][2];
#pragma unroll
            for (int rf = 0; rf < 2; ++rf)
#pragma unroll
                for (int ks = 0; ks < 2; ++ks)
                    pf[rf][ks] = ld16(&Pl[w][rf * 16 + l16][ks * 32 + l4 * 8]);
#pragma unroll
            for (int dt = 0; dt < 8; ++dt) {
#pragma unroll
                for (int ks = 0; ks < 2; ++ks) {
                    bf16x8 vfr = ld16(vtb + (size_t)(dt * 16 + l16) * LSEQ + kt + ks * 32 + l4 * 8);
#pragma unroll
                    for (int rf = 0; rf < 2; ++rf)
                        oacc[rf][dt] = __builtin_amdgcn_mfma_f32_16x16x32_bf16(pf[rf][ks], vfr, oacc[rf][dt], 0, 0, 0);
                }
            }
        }

#pragma unroll
        for (int rf = 0; rf < 2; ++rf)
#pragma unroll
            for (int r = 0; r < 4; ++r) lr[rf][r] = 1.0f / lr[rf][r];
        int trow = b * LSEQ + q0;
#pragma unroll
        for (int rf = 0; rf < 2; ++rf)
#pragma unroll
            for (int dt = 0; dt < 8; ++dt)
#pragma unroll
                for (int r = 0; r < 4; ++r) {
                    int t = trow + rf * 16 + l4 * 4 + r;
                    O[(size_t)t * HID + h * HD + dt * 16 + l16] = f2b(oacc[rf][dt][r] * lr[rf][r]);
                }
    }
}

// ---------------- launch -----------------------------------------------------
extern "C" void kernel_launch(void* const* d_in, const int* in_sizes, int n_in,
                              void* d_out, int out_size, void* d_ws, size_t ws_size,
                              hipStream_t stream) {
    const float* x    = (const float*)d_in[0];
    const float* cosT = (const float*)d_in[1];
    const float* sinT = (const float*)d_in[2];
    const int* und = (const int*)d_in[4];
    const int* gen = (const int*)d_in[5];
    const float* Wq_u = (const float*)d_in[6];
    const float* bq_u = (const float*)d_in[7];
    const float* Wk_u = (const float*)d_in[8];
    const float* bk_u = (const float*)d_in[9];
    const float* Wv_u = (const float*)d_in[10];
    const float* bv_u = (const float*)d_in[11];
    const float* Wo_u = (const float*)d_in[12];
    const float* Wq_g = (const float*)d_in[13];
    const float* bq_g = (const float*)d_in[14];
    const float* Wk_g = (const float*)d_in[15];
    const float* bk_g = (const float*)d_in[16];
    const float* Wv_g = (const float*)d_in[17];
    const float* bv_g = (const float*)d_in[18];
    const float* Wo_g = (const float*)d_in[19];
    const float* qn_u = (const float*)d_in[20];
    const float* kn_u = (const float*)d_in[21];
    const float* qn_g = (const float*)d_in[22];
    const float* kn_g = (const float*)d_in[23];
    float* out = (float*)d_out;

    char* ws = (char*)d_ws;
    size_t off = 0;
    auto alloc = [&](size_t bytes) -> void* {
        void* p = ws + off;
        off += (bytes + 255) & ~(size_t)255;
        return p;
    };
    bf16* xb      = (bf16*)alloc((size_t)T_TOK * HID * 2);
    bf16* Wqkv_u  = (bf16*)alloc((size_t)QKV_N * KDIM * 2);
    bf16* Wqkv_g  = (bf16*)alloc((size_t)QKV_N * KDIM * 2);
    bf16* Wob_u   = (bf16*)alloc((size_t)HID * HID * 2);
    bf16* Wob_g   = (bf16*)alloc((size_t)HID * HID * 2);
    int*  mod     = (int*)alloc((size_t)T_TOK * 4);
    bf16* qkv     = (bf16*)alloc((size_t)T_TOK * QKV_N * 2);
    bf16* Qa      = (bf16*)alloc((size_t)BATCH * NH  * LSEQ * HD * 2);
    bf16* Ka      = (bf16*)alloc((size_t)BATCH * NKV * LSEQ * HD * 2);
    bf16* Vt      = (bf16*)alloc((size_t)BATCH * NKV * HD * LSEQ * 2);
    bf16* Ob      = (bf16*)alloc((size_t)T_TOK * HID * 2);
    (void)ws_size; (void)in_sizes; (void)n_in; (void)out_size;

    // converts
    k_f2b<<<1024, 256, 0, stream>>>(x, xb, T_TOK * HID);
    k_f2b<<<1024, 256, 0, stream>>>(Wq_u, Wqkv_u,               2048 * 2048);
    k_f2b<<<1024, 256, 0, stream>>>(Wk_u, Wqkv_u + 2048 * 2048, 1024 * 2048);
    k_f2b<<<1024, 256, 0, stream>>>(Wv_u, Wqkv_u + 3072 * 2048, 1024 * 2048);
    k_f2b<<<1024, 256, 0, stream>>>(Wq_g, Wqkv_g,               2048 * 2048);
    k_f2b<<<1024, 256, 0, stream>>>(Wk_g, Wqkv_g + 2048 * 2048, 1024 * 2048);
    k_f2b<<<1024, 256, 0, stream>>>(Wv_g, Wqkv_g + 3072 * 2048, 1024 * 2048);
    k_f2b<<<1024, 256, 0, stream>>>(Wo_u, Wob_u, 2048 * 2048);
    k_f2b<<<1024, 256, 0, stream>>>(Wo_g, Wob_g, 2048 * 2048);
    k_mod<<<16, 256, 0, stream>>>(und, gen, mod, T_TOK / 2);

    // routed QKV projections (M=4096, N=4096, K=2048; both modalities)
    k_gemm<0><<<dim3(32 * 32, 2), 256, 0, stream>>>(
        xb, Wqkv_u, Wqkv_g, und, gen, bq_u, bk_u, bv_u, bq_g, bk_g, bv_g,
        qkv, nullptr, 32);

    // RMS + RoPE (Q,K) and V transpose
    k_normrope<<<T_TOK, 256, 0, stream>>>(qkv, cosT, sinT, mod,
                                          qn_u, qn_g, kn_u, kn_g, Qa, Ka);
    k_vt<<<dim3(BATCH * NKV, LSEQ / 64, HD / 64), 256, 0, stream>>>(qkv, Vt);

    // causal GQA attention (balanced pairing: 512 uniform blocks)
    k_attn<<<BATCH * NH * 4, 256, 0, stream>>>(Qa, Ka, Vt, Ob);

    // routed output projections (M=4096, N=2048, K=2048; both modalities)
    k_gemm<1><<<dim3(32 * 16, 2), 256, 0, stream>>>(
        Ob, Wob_u, Wob_g, und, gen, nullptr, nullptr, nullptr,
        nullptr, nullptr, nullptr, nullptr, out, 16);
}

// Round 4
// 493.316 us; speedup vs baseline: 1.7196x; 1.1080x over previous
//
#include <hip/hip_runtime.h>
#include <hip/hip_bf16.h>
#include <stdint.h>
#include <math.h>

#define T_TOK 8192
#define HID   2048
#define NH    16
#define NKV   8
#define HD    128
#define LSEQ  1024
#define BATCH 8
#define QKV_N 4096
#define KDIM  2048
#define NTK   32          // K-tiles of 64 over KDIM=2048
#define SCALE 0.08838834764831845f   // 1/sqrt(128)

typedef __hip_bfloat16 bf16;
typedef __bf16 bf16x8 __attribute__((ext_vector_type(8)));
typedef float  f32x4  __attribute__((ext_vector_type(4)));

typedef const void __attribute__((address_space(1)))* gas_ptr;
typedef void       __attribute__((address_space(3)))* las_ptr;

__device__ __forceinline__ float b2f(bf16 x) { return __bfloat162float(x); }
__device__ __forceinline__ bf16  f2b(float x) { return __float2bfloat16(x); }
__device__ __forceinline__ unsigned short f2u(float x) {
    union { bf16 b; unsigned short u; } c; c.b = __float2bfloat16(x); return c.u;
}

__device__ __forceinline__ bf16x8 ld16(const bf16* p) {
    union { uint4 u; bf16x8 v; } c;
    c.u = *reinterpret_cast<const uint4*>(p);
    return c.v;
}

// async 16B/lane global->LDS. lds must be wave-uniform base; HW adds lane*16.
__device__ __forceinline__ void cp16(void* lds, const void* g) {
    __builtin_amdgcn_global_load_lds((gas_ptr)g, (las_ptr)lds, 16, 0, 0);
}

// ---------------- fp32 -> bf16 convert (grid-stride, vectorized) -------------
__global__ __launch_bounds__(256) void k_f2b(const float* __restrict__ in,
                                             bf16* __restrict__ out, int n) {
    int i = blockIdx.x * blockDim.x + threadIdx.x;
    int stride = gridDim.x * blockDim.x;
    const float4* in4 = (const float4*)in;
    ushort4* out4 = (ushort4*)out;
    int n4 = n >> 2;
    for (int j = i; j < n4; j += stride) {
        float4 v = in4[j];
        ushort4 o;
        o.x = f2u(v.x); o.y = f2u(v.y); o.z = f2u(v.z); o.w = f2u(v.w);
        out4[j] = o;
    }
}

// ---------------- modality map ----------------------------------------------
__global__ __launch_bounds__(256) void k_mod(const int* __restrict__ und,
                                             const int* __restrict__ gen,
                                             int* __restrict__ mod, int n) {
    int i = blockIdx.x * blockDim.x + threadIdx.x;
    if (i < n) { mod[und[i]] = 0; mod[gen[i]] = 1; }
}

// ---------------- routed GEMM: 256x256 tile, BK=64, 8 waves, counted vmcnt ---
// C[idx[row]][col] = sum_k A[idx[row]][k] * Bw[col][k]  (+ bias, EPI==0)
// LDS 128KB dynamic: 2 buffers x {A 256x64, B 256x64} bf16, linear layout for
// global_load_lds; T2 swizzle via XOR on the 16B-chunk index applied to BOTH
// the global source column (staging) and the ds_read column (rule #21).
// Pipeline: stage t0,t1; per iter: vmcnt(8) [t resident, t+1 in flight] ->
// s_barrier -> 64 MFMA -> s_barrier -> stage t+2 into freed buffer.
template<int EPI>
__global__ __launch_bounds__(512)
void k_gemm256(const bf16* __restrict__ A,
               const bf16* __restrict__ Bw_u, const bf16* __restrict__ Bw_g,
               const int* __restrict__ und, const int* __restrict__ gen,
               const float* __restrict__ bq_u, const float* __restrict__ bk_u,
               const float* __restrict__ bv_u,
               const float* __restrict__ bq_g, const float* __restrict__ bk_g,
               const float* __restrict__ bv_g,
               bf16* __restrict__ outB, float* __restrict__ outF) {
    extern __shared__ char smem[];

    int modg = blockIdx.y;
    const bf16* Bw = modg ? Bw_g : Bw_u;
    const int* idx = modg ? gen : und;
    const float* bq = modg ? bq_g : bq_u;
    const float* bk = modg ? bk_g : bk_u;
    const float* bv = modg ? bv_g : bv_u;

    // XCD swizzle (gridDim.x % 8 == 0), tn-major so each XCD reuses 2 B-panels
    int gx = gridDim.x;
    int bid = blockIdx.x;
    int sw = (bid & 7) * (gx >> 3) + (bid >> 3);
    int tn = sw >> 4;          // ntm = 16 (M = 4096 fixed)
    int tm = sw & 15;

    int tid = threadIdx.x;
    int w = tid >> 6, lane = tid & 63;
    int l16 = lane & 15, l4 = lane >> 4;
    int wm = w >> 2, wn = w & 3;      // 2 x 4 waves -> 128 x 64 per wave

    // ---- staging setup: thread writes LDS row (i*64 + tid>>3), chunk tid&7
    int srow = tid >> 3;                   // 0..63
    int schunk = (tid & 7) ^ (srow & 7);   // inverse-swizzled source chunk
    const bf16* aSrc[4];
    const bf16* bSrc[4];
#pragma unroll
    for (int i = 0; i < 4; ++i) {
        int ar = tm * 256 + i * 64 + srow;
        aSrc[i] = A + (size_t)idx[ar] * KDIM + schunk * 8;
        bSrc[i] = Bw + (size_t)(tn * 256 + i * 64 + srow) * KDIM + schunk * 8;
    }

    auto STAGE = [&](int t) {
        char* Ab = smem + (t & 1) * 65536;
        char* Bb = Ab + 32768;
#pragma unroll
        for (int i = 0; i < 4; ++i) {
            cp16(Ab + i * 8192 + w * 1024, aSrc[i] + t * 64);
            cp16(Bb + i * 8192 + w * 1024, bSrc[i] + t * 64);
        }
    };

    f32x4 acc[8][4];
#pragma unroll
    for (int m = 0; m < 8; ++m)
#pragma unroll
        for (int n = 0; n < 4; ++n) acc[m][n] = {0.f, 0.f, 0.f, 0.f};

    STAGE(0);
    STAGE(1);

    uint32_t aRowByte = (uint32_t)(wm * 128 + l16) * 128;   // + m*2048
    uint32_t bRowByte = (uint32_t)(wn * 64 + l16) * 128;    // + n*2048
    uint32_t rx = (uint32_t)(l16 & 7);                      // read-side XOR

#pragma unroll 1
    for (int t = 0; t < NTK; ++t) {
        if (t < NTK - 1) asm volatile("s_waitcnt vmcnt(8)" ::: "memory");
        else             asm volatile("s_waitcnt vmcnt(0)" ::: "memory");
        __builtin_amdgcn_s_barrier();
        asm volatile("" ::: "memory");

        const char* Ab = smem + (t & 1) * 65536;
        const char* Bb = Ab + 32768;
#pragma unroll
        for (int kk = 0; kk < 2; ++kk) {
            uint32_t cByte = ((((uint32_t)(kk << 2) | l4) ^ rx) << 4);
            bf16x8 af[8], bfr[4];
#pragma unroll
            for (int m = 0; m < 8; ++m)
                af[m] = ld16((const bf16*)(Ab + aRowByte + m * 2048 + cByte));
#pragma unroll
            for (int n = 0; n < 4; ++n)
                bfr[n] = ld16((const bf16*)(Bb + bRowByte + n * 2048 + cByte));
            __builtin_amdgcn_s_setprio(1);
#pragma unroll
            for (int m = 0; m < 8; ++m)
#pragma unroll
                for (int n = 0; n < 4; ++n)
                    acc[m][n] = __builtin_amdgcn_mfma_f32_16x16x32_bf16(af[m], bfr[n], acc[m][n], 0, 0, 0);
            __builtin_amdgcn_s_setprio(0);
        }

        asm volatile("" ::: "memory");
        __builtin_amdgcn_s_barrier();
        asm volatile("" ::: "memory");
        if (t + 2 < NTK) STAGE(t + 2);
    }

    int rowbase = tm * 256 + wm * 128;
    int colbase = tn * 256 + wn * 64;
#pragma unroll
    for (int m = 0; m < 8; ++m) {
#pragma unroll
        for (int r = 0; r < 4; ++r) {
            int row = rowbase + m * 16 + l4 * 4 + r;
            int token = idx[row];
#pragma unroll
            for (int n = 0; n < 4; ++n) {
                int col = colbase + n * 16 + l16;
                float v = acc[m][n][r];
                if (EPI == 0) {
                    float bias = (col < 2048) ? bq[col]
                               : (col < 3072) ? bk[col - 2048] : bv[col - 3072];
                    outB[(size_t)token * QKV_N + col] = f2b(v + bias);
                } else {
                    outF[(size_t)token * HID + col] = v;
                }
            }
        }
    }
}

// ---------------- per-head RMSNorm + RoPE (Q,K only) -------------------------
__global__ __launch_bounds__(256)
void k_normrope(const bf16* __restrict__ qkv,
                const float* __restrict__ cosT, const float* __restrict__ sinT,
                const int* __restrict__ mod,
                const float* __restrict__ qn_u, const float* __restrict__ qn_g,
                const float* __restrict__ kn_u, const float* __restrict__ kn_g,
                bf16* __restrict__ Qo, bf16* __restrict__ Ko) {
    int t = blockIdx.x;
    int tid = threadIdx.x;
    int w = tid >> 6, lane = tid & 63;
    int m = mod[t];
    int b = t >> 10, pos = t & 1023;
    const bf16* row = qkv + (size_t)t * QKV_N;
    int d0 = 2 * lane, d1 = 2 * lane + 1;
    float c0 = cosT[(size_t)t * HD + d0], c1 = cosT[(size_t)t * HD + d1];
    float s0 = sinT[(size_t)t * HD + d0], s1 = sinT[(size_t)t * HD + d1];
    float sgn = (lane < 32) ? -1.f : 1.f;
    const float* qw = m ? qn_g : qn_u;
    const float* kw = m ? kn_g : kn_u;

    for (int u = w; u < 24; u += 4) {
        float v0 = b2f(row[u * HD + d0]);
        float v1 = b2f(row[u * HD + d1]);
        float ss = v0 * v0 + v1 * v1;
#pragma unroll
        for (int msk = 1; msk < 64; msk <<= 1) ss += __shfl_xor(ss, msk);
        float rs = rsqrtf(ss * (1.0f / HD) + 1e-6f);
        const float* wsc = (u < 16) ? qw : kw;
        float n0 = v0 * rs * wsc[d0], n1 = v1 * rs * wsc[d1];
        float o0 = __shfl_xor(n0, 32), o1 = __shfl_xor(n1, 32);
        float r0 = n0 * c0 + sgn * o0 * s0;
        float r1 = n1 * c1 + sgn * o1 * s1;
        if (u < 16) {
            size_t o = ((size_t)(b * NH + u) * LSEQ + pos) * HD;
            Qo[o + d0] = f2b(r0); Qo[o + d1] = f2b(r1);
        } else {
            size_t o = ((size_t)(b * NKV + (u - 16)) * LSEQ + pos) * HD;
            Ko[o + d0] = f2b(r0); Ko[o + d1] = f2b(r1);
        }
    }
}

// ---------------- V transpose: qkv[t][3072+kv*128+d] -> Vt[b,kv][d][pos] -----
__global__ __launch_bounds__(256)
void k_vt(const bf16* __restrict__ qkv, bf16* __restrict__ Vt) {
    __shared__ bf16 lds[64][72];
    int bk = blockIdx.x;
    int b = bk >> 3, kv = bk & 7;
    int pos0 = blockIdx.y * 64;
    int d0 = blockIdx.z * 64;
    int tid = threadIdx.x;

#pragma unroll
    for (int it = 0; it < 2; ++it) {
        int c = tid + it * 256;
        int row = c >> 3, col8 = (c & 7) * 8;
        const bf16* src = qkv + (size_t)(b * LSEQ + pos0 + row) * QKV_N
                        + 3072 + kv * HD + d0 + col8;
        *reinterpret_cast<uint4*>(&lds[row][col8]) = *reinterpret_cast<const uint4*>(src);
    }
    __syncthreads();

#pragma unroll
    for (int it = 0; it < 2; ++it) {
        int c = tid + it * 256;
        int drow = c & 63, pos8 = (c >> 6) * 8;
        union { unsigned short s[8]; uint4 u; } g;
#pragma unroll
        for (int j = 0; j < 8; ++j)
            g.s[j] = *reinterpret_cast<const unsigned short*>(&lds[pos8 + j][drow]);
        bf16* dst = Vt + ((size_t)bk * HD + d0 + drow) * LSEQ + pos0 + pos8;
        *reinterpret_cast<uint4*>(dst) = g.u;
    }
}

// ---------------- causal GQA flash attention (balanced, 32 q-rows/wave) ------
__global__ __launch_bounds__(256)
void k_attn(const bf16* __restrict__ Q, const bf16* __restrict__ K,
            const bf16* __restrict__ Vt, bf16* __restrict__ O) {
    int bid = blockIdx.x;
    int p = bid & 3;
    int h = (bid >> 2) & 15;
    int b = bid >> 6;
    int tid = threadIdx.x;
    int w = tid >> 6, lane = tid & 63;
    int l16 = lane & 15, l4 = lane >> 4;
    int j = p * 4 + w;

    const bf16* qhb = Q + (size_t)(b * NH + h) * LSEQ * HD;
    int kv = h >> 1;
    const bf16* kb = K + (size_t)(b * NKV + kv) * LSEQ * HD;
    const bf16* vtb = Vt + (size_t)(b * NKV + kv) * HD * LSEQ;

    __shared__ bf16 Pl[4][32][72];

    f32x4 zero = {0.f, 0.f, 0.f, 0.f};

#pragma unroll 1
    for (int half = 0; half < 2; ++half) {
        int rowblk = half ? (31 - j) : j;
        int q0 = rowblk * 32;
        int kend = q0 + 32;

        bf16x8 qf[2][4];
#pragma unroll
        for (int rf = 0; rf < 2; ++rf)
#pragma unroll
            for (int c = 0; c < 4; ++c)
                qf[rf][c] = ld16(qhb + (size_t)(q0 + rf * 16 + l16) * HD + c * 32 + l4 * 8);

        f32x4 oacc[2][8];
#pragma unroll
        for (int rf = 0; rf < 2; ++rf)
#pragma unroll
            for (int d = 0; d < 8; ++d) oacc[rf][d] = zero;
        float mr[2][4], lr[2][4];
#pragma unroll
        for (int rf = 0; rf < 2; ++rf)
#pragma unroll
            for (int r = 0; r < 4; ++r) { mr[rf][r] = -INFINITY; lr[rf][r] = 0.f; }

        for (int kt = 0; kt < kend; kt += 64) {
            f32x4 s[2][4];
#pragma unroll
            for (int rf = 0; rf < 2; ++rf)
#pragma unroll
                for (int kf = 0; kf < 4; ++kf) s[rf][kf] = zero;
#pragma unroll
            for (int c = 0; c < 4; ++c) {
                bf16x8 kf4[4];
#pragma unroll
                for (int kf = 0; kf < 4; ++kf)
                    kf4[kf] = ld16(kb + (size_t)(kt + kf * 16 + l16) * HD + c * 32 + l4 * 8);
#pragma unroll
                for (int rf = 0; rf < 2; ++rf)
#pragma unroll
                    for (int kf = 0; kf < 4; ++kf)
                        s[rf][kf] = __builtin_amdgcn_mfma_f32_16x16x32_bf16(qf[rf][c], kf4[kf], s[rf][kf], 0, 0, 0);
            }
#pragma unroll
            for (int rf = 0; rf < 2; ++rf) {
#pragma unroll
                for (int r = 0; r < 4; ++r) {
                    int qrow = q0 + rf * 16 + l4 * 4 + r;
                    float sc[4];
                    float rm = -1e30f;
#pragma unroll
                    for (int kf = 0; kf < 4; ++kf) {
                        int key = kt + kf * 16 + l16;
                        sc[kf] = (key <= qrow) ? s[rf][kf][r] * SCALE : -1e30f;
                        rm = fmaxf(rm, sc[kf]);
                    }
#pragma unroll
                    for (int msk = 1; msk < 16; msk <<= 1) rm = fmaxf(rm, __shfl_xor(rm, msk));
                    float mn = fmaxf(mr[rf][r], rm);
                    float corr = __expf(mr[rf][r] - mn);
                    mr[rf][r] = mn;
                    float rsum = 0.f;
#pragma unroll
                    for (int kf = 0; kf < 4; ++kf) {
                        float pv = __expf(sc[kf] - mn);
                        rsum += pv;
                        Pl[w][rf * 16 + l4 * 4 + r][kf * 16 + l16] = f2b(pv);
                    }
#pragma unroll
                    for (int msk = 1; msk < 16; msk <<= 1) rsum += __shfl_xor(rsum, msk);
                    lr[rf][r] = lr[rf][r] * corr + rsum;
#pragma unroll
                    for (int d = 0; d < 8; ++d) oacc[rf][d][r] *= corr;
                }
            }
            bf16x8 pf[2][2];
#pragma unroll
            for (int rf = 0; rf < 2; ++rf)
#pragma unroll
                for (int ks = 0; ks < 2; ++ks)
                    pf[rf][ks] = ld16(&Pl[w][rf * 16 + l16][ks * 32 + l4 * 8]);
#pragma unroll
            for (int dt = 0; dt < 8; ++dt) {
#pragma unroll
                for (int ks = 0; ks < 2; ++ks) {
                    bf16x8 vfr = ld16(vtb + (size_t)(dt * 16 + l16) * LSEQ + kt + ks * 32 + l4 * 8);
#pragma unroll
                    for (int rf = 0; rf < 2; ++rf)
                        oacc[rf][dt] = __builtin_amdgcn_mfma_f32_16x16x32_bf16(pf[rf][ks], vfr, oacc[rf][dt], 0, 0, 0);
                }
            }
        }

#pragma unroll
        for (int rf = 0; rf < 2; ++rf)
#pragma unroll
            for (int r = 0; r < 4; ++r) lr[rf][r] = 1.0f / lr[rf][r];
        int trow = b * LSEQ + q0;
#pragma unroll
        for (int rf = 0; rf < 2; ++rf)
#pragma unroll
            for (int dt = 0; dt < 8; ++dt)
#pragma unroll
                for (int r = 0; r < 4; ++r) {
                    int t = trow + rf * 16 + l4 * 4 + r;
                    O[(size_t)t * HID + h * HD + dt * 16 + l16] = f2b(oacc[rf][dt][r] * lr[rf][r]);
                }
    }
}

// ---------------- launch -----------------------------------------------------
extern "C" void kernel_launch(void* const* d_in, const int* in_sizes, int n_in,
                              void* d_out, int out_size, void* d_ws, size_t ws_size,
                              hipStream_t stream) {
    const float* x    = (const float*)d_in[0];
    const float* cosT = (const float*)d_in[1];
    const float* sinT = (const float*)d_in[2];
    const int* und = (const int*)d_in[4];
    const int* gen = (const int*)d_in[5];
    const float* Wq_u = (const float*)d_in[6];
    const float* bq_u = (const float*)d_in[7];
    const float* Wk_u = (const float*)d_in[8];
    const float* bk_u = (const float*)d_in[9];
    const float* Wv_u = (const float*)d_in[10];
    const float* bv_u = (const float*)d_in[11];
    const float* Wo_u = (const float*)d_in[12];
    const float* Wq_g = (const float*)d_in[13];
    const float* bq_g = (const float*)d_in[14];
    const float* Wk_g = (const float*)d_in[15];
    const float* bk_g = (const float*)d_in[16];
    const float* Wv_g = (const float*)d_in[17];
    const float* bv_g = (const float*)d_in[18];
    const float* Wo_g = (const float*)d_in[19];
    const float* qn_u = (const float*)d_in[20];
    const float* kn_u = (const float*)d_in[21];
    const float* qn_g = (const float*)d_in[22];
    const float* kn_g = (const float*)d_in[23];
    float* out = (float*)d_out;

    char* ws = (char*)d_ws;
    size_t off = 0;
    auto alloc = [&](size_t bytes) -> void* {
        void* p = ws + off;
        off += (bytes + 255) & ~(size_t)255;
        return p;
    };
    bf16* xb      = (bf16*)alloc((size_t)T_TOK * HID * 2);
    bf16* Wqkv_u  = (bf16*)alloc((size_t)QKV_N * KDIM * 2);
    bf16* Wqkv_g  = (bf16*)alloc((size_t)QKV_N * KDIM * 2);
    bf16* Wob_u   = (bf16*)alloc((size_t)HID * HID * 2);
    bf16* Wob_g   = (bf16*)alloc((size_t)HID * HID * 2);
    int*  mod     = (int*)alloc((size_t)T_TOK * 4);
    bf16* qkv     = (bf16*)alloc((size_t)T_TOK * QKV_N * 2);
    bf16* Qa      = (bf16*)alloc((size_t)BATCH * NH  * LSEQ * HD * 2);
    bf16* Ka      = (bf16*)alloc((size_t)BATCH * NKV * LSEQ * HD * 2);
    bf16* Vt      = (bf16*)alloc((size_t)BATCH * NKV * HD * LSEQ * 2);
    bf16* Ob      = (bf16*)alloc((size_t)T_TOK * HID * 2);
    (void)ws_size; (void)in_sizes; (void)n_in; (void)out_size;

    // allow 128KB dynamic LDS for the GEMM kernels (idempotent, capture-safe)
    (void)hipFuncSetAttribute((const void*)k_gemm256<0>,
                              hipFuncAttributeMaxDynamicSharedMemorySize, 131072);
    (void)hipFuncSetAttribute((const void*)k_gemm256<1>,
                              hipFuncAttributeMaxDynamicSharedMemorySize, 131072);

    // converts
    k_f2b<<<1024, 256, 0, stream>>>(x, xb, T_TOK * HID);
    k_f2b<<<1024, 256, 0, stream>>>(Wq_u, Wqkv_u,               2048 * 2048);
    k_f2b<<<1024, 256, 0, stream>>>(Wk_u, Wqkv_u + 2048 * 2048, 1024 * 2048);
    k_f2b<<<1024, 256, 0, stream>>>(Wv_u, Wqkv_u + 3072 * 2048, 1024 * 2048);
    k_f2b<<<1024, 256, 0, stream>>>(Wq_g, Wqkv_g,               2048 * 2048);
    k_f2b<<<1024, 256, 0, stream>>>(Wk_g, Wqkv_g + 2048 * 2048, 1024 * 2048);
    k_f2b<<<1024, 256, 0, stream>>>(Wv_g, Wqkv_g + 3072 * 2048, 1024 * 2048);
    k_f2b<<<1024, 256, 0, stream>>>(Wo_u, Wob_u, 2048 * 2048);
    k_f2b<<<1024, 256, 0, stream>>>(Wo_g, Wob_g, 2048 * 2048);
    k_mod<<<16, 256, 0, stream>>>(und, gen, mod, T_TOK / 2);

    // routed QKV projections (M=4096, N=4096, K=2048; both modalities)
    k_gemm256<0><<<dim3(16 * 16, 2), 512, 131072, stream>>>(
        xb, Wqkv_u, Wqkv_g, und, gen, bq_u, bk_u, bv_u, bq_g, bk_g, bv_g,
        qkv, nullptr);

    // RMS + RoPE (Q,K) and V transpose
    k_normrope<<<T_TOK, 256, 0, stream>>>(qkv, cosT, sinT, mod,
                                          qn_u, qn_g, kn_u, kn_g, Qa, Ka);
    k_vt<<<dim3(BATCH * NKV, LSEQ / 64, HD / 64), 256, 0, stream>>>(qkv, Vt);

    // causal GQA attention (balanced pairing: 512 uniform blocks)
    k_attn<<<BATCH * NH * 4, 256, 0, stream>>>(Qa, Ka, Vt, Ob);

    // routed output projections (M=4096, N=2048, K=2048; both modalities)
    k_gemm256<1><<<dim3(8 * 16, 2), 512, 131072, stream>>>(
        Ob, Wob_u, Wob_g, und, gen, nullptr, nullptr, nullptr,
        nullptr, nullptr, nullptr, nullptr, out);
}